// Round 5
// baseline (277.757 us; speedup 1.0000x reference)
//
#include <hip/hip_runtime.h>
#include <math.h>

// ---------------- LDS layout (floats), 128-thread (2-wave) block, 1 sample ----
#define WC3  0      // l1c3 [q3][m4][n4][q4]            128
#define WC2  128    // l1c2 [q2][m3][n3][q3]            128
#define WU1  256    // l2c1                              32  -> 288
#define T2A  288    // per-wave T2: wave v at T2A+v*1152, rows [32][36]  -> 2592
#define T3S  2592   // shared T3 rows [32][34] = 1088   -> 3680
#define HZ   288    // h1 zone (128 rows x 17 = 2176) overlays T2/T3 after layer-1
#define DZ32 32     // D row s at HZ + 136*s + 32 (16 cols)
#define H3O  (HZ + 2112)   // 32  (C row 31 dead by then)
#define H2O  (HZ + 2176)   // 64
#define LDS_FLOATS 3680    // 14720 B -> 8 blocks/CU easily

// Setup: dense layer-3 matrix W3[mi(32)][nj(64)] from TT cores (tiny).
__global__ void tt_setup_w3(const float* __restrict__ v0, const float* __restrict__ v1,
                            const float* __restrict__ v2, const float* __restrict__ v3,
                            const float* __restrict__ v4, float* __restrict__ w3) {
    int i = blockIdx.x * 256 + threadIdx.x;
    if (i >= 2048) return;
    int mi = i >> 6, nj = i & 63;
    int m1 = (mi >> 4) & 1, m2 = (mi >> 3) & 1, m3 = (mi >> 2) & 1, m4 = (mi >> 1) & 1, m5 = mi & 1;
    int n1 = (nj >> 4) & 3, n2 = (nj >> 3) & 1, n3 = (nj >> 2) & 1, n4 = (nj >> 1) & 1, n5 = nj & 1;
    float s = 0.f;
#pragma unroll
    for (int q1 = 0; q1 < 2; ++q1) {
        float a1 = v0[(m1 * 4 + n1) * 2 + q1];
#pragma unroll
        for (int q2 = 0; q2 < 2; ++q2) {
            float a2 = a1 * v1[((q1 * 2 + m2) * 2 + n2) * 2 + q2];
#pragma unroll
            for (int q3 = 0; q3 < 2; ++q3) {
                float a3 = a2 * v2[((q2 * 2 + m3) * 2 + n3) * 2 + q3];
#pragma unroll
                for (int q4 = 0; q4 < 2; ++q4)
                    s = fmaf(a3 * v3[((q3 * 2 + m4) * 2 + n4) * 2 + q4],
                             v4[(q4 * 2 + m5) * 2 + n5], s);
            }
        }
    }
    w3[i] = s;
}

__global__ __launch_bounds__(128, 4)
void tt_main(const float* __restrict__ x,
             const float* __restrict__ g0, const float* __restrict__ g1,
             const float* __restrict__ g2, const float* __restrict__ g3,
             const float* __restrict__ g4, const float* __restrict__ b1g,
             const float* __restrict__ u0, const float* __restrict__ u1,
             const float* __restrict__ u2, const float* __restrict__ u3,
             const float* __restrict__ u4, const float* __restrict__ b2g,
             const float* __restrict__ b3g,
             const float* __restrict__ Wmg, const float* __restrict__ blg,
             const float* __restrict__ w3g,
             float* __restrict__ out)
{
    __shared__ float smem[LDS_FLOATS];
    const int t = threadIdx.x;
    const int v = t >> 6;          // wave id = n2h handled by this wave
    const int l = t & 63;          // lane within wave
    const int b = blockIdx.x;
    const float* xb = x + (size_t)b * 12288;

    // ---- non-uniformly-indexed weights to LDS (shared) ----
    smem[WC3 + t] = g3[t];
    smem[WC2 + t] = g2[t];
    if (t < 32) smem[WU1 + t] = u1[t];
    __syncthreads();

    const int h = l & 1;               // n4-half owned by this lane
    const int p = l >> 1;              // subslice-local prefix (n2l*8 + n3)
    const int rho = (p & 7) * 4 + (p >> 3);   // T2 row = n3*4 + n2l
    const int T2W = T2A + v * 1152;

    float regT4[18];                   // [jjl(2)][n1(3)][q1(3)]
#pragma unroll
    for (int i = 0; i < 18; ++i) regT4[i] = 0.f;

#pragma unroll
    for (int n1 = 0; n1 < 3; ++n1) {
        const int s = n1 * 2 + v;      // this wave's subslice
        // ---- load x slab (32 contiguous floats per lane) ----
        float xv[32];
        {
            const float4* xq = (const float4*)(xb + s * 2048 + l * 32);
#pragma unroll
            for (int i = 0; i < 8; ++i) {
                const float4 q = xq[i];
                xv[i*4+0] = q.x; xv[i*4+1] = q.y; xv[i*4+2] = q.z; xv[i*4+3] = q.w;
            }
        }
        // ---- step 1: t1[n4l*8 + m5*2+q4] = sum_n5 x*C4 (C4 uniform s_load) ----
        float t1[32];
#pragma unroll
        for (int m5 = 0; m5 < 4; ++m5)
#pragma unroll
        for (int q4 = 0; q4 < 2; ++q4) {
            const float* w = g4 + (q4 * 4 + m5) * 8;
#pragma unroll
            for (int n4l = 0; n4l < 4; ++n4l) {
                float sa = xv[n4l*8+0] * w[0];
#pragma unroll
                for (int n5 = 1; n5 < 8; ++n5) sa = fmaf(xv[n4l*8+n5], w[n5], sa);
                t1[n4l*8 + m5*2 + q4] = sa;
            }
        }
        // ---- step 2: acc[m4*4+m5] (q3=h); contract n4 (own half + partner) ----
        float acc[16];
#pragma unroll
        for (int i = 0; i < 16; ++i) acc[i] = 0.f;
#pragma unroll
        for (int pass = 0; pass < 2; ++pass) {
            const int hh = (pass == 0) ? h : (1 - h);
            if (pass == 1) {
#pragma unroll
                for (int i = 0; i < 32; ++i) t1[i] = __shfl_xor(t1[i], 1);
            }
#pragma unroll
            for (int m4 = 0; m4 < 4; ++m4) {
                const int cbase = WC3 + ((h * 4 + m4) * 8 + hh * 4) * 2;
                const float4 c0 = *(const float4*)&smem[cbase];
                const float4 c1 = *(const float4*)&smem[cbase + 4];
                const float cs[8] = {c0.x, c0.y, c0.z, c0.w, c1.x, c1.y, c1.z, c1.w};
#pragma unroll
                for (int m5 = 0; m5 < 4; ++m5) {
                    float sa = acc[m4*4+m5];
#pragma unroll
                    for (int n4l = 0; n4l < 4; ++n4l)
#pragma unroll
                    for (int q4 = 0; q4 < 2; ++q4)
                        sa = fmaf(t1[n4l*8 + m5*2 + q4], cs[n4l*2 + q4], sa);
                    acc[m4*4+m5] = sa;
                }
            }
        }
#pragma unroll
        for (int m45 = 0; m45 < 16; ++m45)
            smem[T2W + rho * 36 + m45 * 2 + h] = acc[m45];
        __syncthreads();   // T2 ready

        // ---- step 3: contract n3(half per lane),q3 -> T3 rows (n2*4+m3) ----
        {
            const int n3h = l & 1;
            const int q2  = (l >> 1) & 1;
            const int m3  = (l >> 2) & 3;
            const int n2l = l >> 4;
            float o3[16];
#pragma unroll
            for (int i = 0; i < 16; ++i) o3[i] = 0.f;
#pragma unroll
            for (int n3l = 0; n3l < 4; ++n3l) {
                const int n3 = n3h * 4 + n3l;
                const int rb = T2W + (n3 * 4 + n2l) * 36;
                float rv[32];
#pragma unroll
                for (int g = 0; g < 8; ++g) {
                    const float4 q = *(const float4*)&smem[rb + g * 4];
                    rv[g*4+0] = q.x; rv[g*4+1] = q.y; rv[g*4+2] = q.z; rv[g*4+3] = q.w;
                }
                const int wb = WC2 + ((q2 * 4 + m3) * 8 + n3) * 2;
                const float w0 = smem[wb], w1 = smem[wb + 1];
#pragma unroll
                for (int m45 = 0; m45 < 16; ++m45)
                    o3[m45] = fmaf(rv[m45*2], w0, fmaf(rv[m45*2+1], w1, o3[m45]));
            }
#pragma unroll
            for (int k = 0; k < 16; ++k) o3[k] += __shfl_xor(o3[k], 1);
            const int row3 = (v * 4 + n2l) * 4 + m3;       // n2*4 + m3
#pragma unroll
            for (int k = 0; k < 8; ++k) {
                const float val = n3h ? o3[8 + k] : o3[k];
                smem[T3S + row3 * 34 + (n3h * 8 + k) * 2 + q2] = val;
            }
        }
        __syncthreads();   // T3 ready (cross-wave)

        // ---- step 4: contract n2(8),q2 -> regT4 (C1 uniform s_load) ----
        {
            const int m3 = l >> 4, m4 = (l >> 2) & 3, m5 = l & 3;
            float2 zz[8];
#pragma unroll
            for (int n2 = 0; n2 < 8; ++n2)
                zz[n2] = *(const float2*)&smem[T3S + (n2 * 4 + m3) * 34 + (m4 * 4 + m5) * 2];
#pragma unroll
            for (int jjl = 0; jjl < 2; ++jjl) {
                const int jj = v * 2 + jjl;
#pragma unroll
                for (int q1 = 0; q1 < 3; ++q1) {
                    float sa = regT4[(jjl * 3 + n1) * 3 + q1];
#pragma unroll
                    for (int n2g = 0; n2g < 4; ++n2g) {
                        const float4 w = *(const float4*)(g1 + ((q1 * 4 + jj) * 8 + n2g * 2) * 2);
                        sa = fmaf(zz[n2g*2].x,   w.x, sa);
                        sa = fmaf(zz[n2g*2].y,   w.y, sa);
                        sa = fmaf(zz[n2g*2+1].x, w.z, sa);
                        sa = fmaf(zz[n2g*2+1].y, w.w, sa);
                    }
                    regT4[(jjl * 3 + n1) * 3 + q1] = sa;
                }
            }
        }
        __syncthreads();   // step4 reads done; T2/T3 reusable next iter (or HZ)
    } // n1

    // ---- step 5: contract n1,q1 + bias + relu -> h1 (pad-17 rows in HZ) ----
#pragma unroll
    for (int jjl = 0; jjl < 2; ++jjl) {
        const int jj = v * 2 + jjl;
#pragma unroll
        for (int m1 = 0; m1 < 8; ++m1) {
            const int e = m1 * 256 + jj * 64 + l;
            float sa = b1g[e];
#pragma unroll
            for (int n1 = 0; n1 < 3; ++n1)
#pragma unroll
            for (int q1 = 0; q1 < 3; ++q1)
                sa = fmaf(regT4[(jjl * 3 + n1) * 3 + q1], g0[(m1 * 3 + n1) * 3 + q1], sa);
            smem[HZ + (e >> 4) * 17 + (e & 15)] = fmaxf(sa, 0.f);
        }
    }
    __syncthreads();

    // ---- L2a+L2b fused: h1 row p3=t -> B row (in-place, 8 floats) ----
    {
        float hv[16];
#pragma unroll
        for (int k = 0; k < 16; ++k) hv[k] = smem[HZ + t * 17 + k];
        float o[8];
#pragma unroll
        for (int i = 0; i < 8; ++i) o[i] = 0.f;
#pragma unroll
        for (int n4 = 0; n4 < 4; ++n4) {
            float a[4];   // [m5*2+q4]
#pragma unroll
            for (int m5 = 0; m5 < 2; ++m5)
#pragma unroll
            for (int q4 = 0; q4 < 2; ++q4) {
                float sa = hv[n4*4+0] * u4[(q4 * 2 + m5) * 4 + 0];
#pragma unroll
                for (int n5 = 1; n5 < 4; ++n5)
                    sa = fmaf(hv[n4*4+n5], u4[(q4 * 2 + m5) * 4 + n5], sa);
                a[m5 * 2 + q4] = sa;
            }
#pragma unroll
            for (int q4 = 0; q4 < 2; ++q4) {
                const float a0 = a[0 * 2 + q4], a1 = a[1 * 2 + q4];
#pragma unroll
                for (int q3 = 0; q3 < 2; ++q3)
#pragma unroll
                for (int m4 = 0; m4 < 2; ++m4) {
                    const float w = u3[((q3 * 2 + m4) * 4 + n4) * 2 + q4];
                    o[(m4 * 2 + 0) * 2 + q3] = fmaf(a0, w, o[(m4 * 2 + 0) * 2 + q3]);
                    o[(m4 * 2 + 1) * 2 + q3] = fmaf(a1, w, o[(m4 * 2 + 1) * 2 + q3]);
                }
            }
        }
#pragma unroll
        for (int k = 0; k < 8; ++k) smem[HZ + t * 17 + k] = o[k];
    }
    __syncthreads();

    // ---- L2c: contract n3(4),q3 -> C[p2=t<32][16] at HZ + 68*p2 ----
    if (t < 32) {
        float o[16];
#pragma unroll
        for (int i = 0; i < 16; ++i) o[i] = 0.f;
#pragma unroll
        for (int n3 = 0; n3 < 4; ++n3)
#pragma unroll
        for (int q3 = 0; q3 < 2; ++q3) {
            float zb[4];
#pragma unroll
            for (int m45 = 0; m45 < 4; ++m45)
                zb[m45] = smem[HZ + (t * 4 + n3) * 17 + m45 * 2 + q3];
#pragma unroll
            for (int m3 = 0; m3 < 2; ++m3)
#pragma unroll
            for (int q2 = 0; q2 < 2; ++q2) {
                const float w = u2[((q2 * 2 + m3) * 4 + n3) * 2 + q3];
#pragma unroll
                for (int m45 = 0; m45 < 4; ++m45)
                    o[(m3 * 4 + m45) * 2 + q2] = fmaf(zb[m45], w, o[(m3 * 4 + m45) * 2 + q2]);
            }
        }
#pragma unroll
        for (int k = 0; k < 16; ++k) smem[HZ + t * 68 + k] = o[k];
    }
    __syncthreads();

    // ---- L2d: contract n2(4),q2 -> D[s=16 rows][16] at HZ + 136*s + 32 ----
    if (t < 32) {
        const int n1 = t >> 2, m2 = (t >> 1) & 1, m3 = t & 1;
        float o[8];   // [m45*2+q1]
#pragma unroll
        for (int i = 0; i < 8; ++i) o[i] = 0.f;
#pragma unroll
        for (int n2 = 0; n2 < 4; ++n2)
#pragma unroll
        for (int q2 = 0; q2 < 2; ++q2) {
            float cb[4];
#pragma unroll
            for (int m45 = 0; m45 < 4; ++m45)
                cb[m45] = smem[HZ + (n1 * 4 + n2) * 68 + (m3 * 4 + m45) * 2 + q2];
#pragma unroll
            for (int q1 = 0; q1 < 2; ++q1) {
                const float w = smem[WU1 + ((q1 * 2 + m2) * 4 + n2) * 2 + q2];
#pragma unroll
                for (int m45 = 0; m45 < 4; ++m45)
                    o[m45 * 2 + q1] = fmaf(cb[m45], w, o[m45 * 2 + q1]);
            }
        }
#pragma unroll
        for (int m45 = 0; m45 < 4; ++m45)
#pragma unroll
        for (int q1 = 0; q1 < 2; ++q1)
            smem[HZ + (m2 * 8 + m3 * 4 + m45) * 136 + DZ32 + n1 * 2 + q1] = o[m45 * 2 + q1];
    }
    __syncthreads();

    // ---- L2e: contract n1(8),q1 + bias + relu -> h2 ----
    if (t < 16) {
        float o[4];
#pragma unroll
        for (int i = 0; i < 4; ++i) o[i] = 0.f;
#pragma unroll
        for (int n1 = 0; n1 < 8; ++n1)
#pragma unroll
        for (int q1 = 0; q1 < 2; ++q1) {
            const float dv = smem[HZ + t * 136 + DZ32 + n1 * 2 + q1];
#pragma unroll
            for (int m1 = 0; m1 < 4; ++m1)
                o[m1] = fmaf(dv, u0[(m1 * 8 + n1) * 2 + q1], o[m1]);
        }
#pragma unroll
        for (int m1 = 0; m1 < 4; ++m1)
            smem[H2O + m1 * 16 + t] = fmaxf(o[m1] + b2g[m1 * 16 + t], 0.f);
    }
    __syncthreads();

    // ---- layer 3 dense (W3 32x64 from d_ws) + relu ----
    if (t < 32) {
        const float4* wr = (const float4*)(w3g + t * 64);
        float sa = b3g[t];
#pragma unroll
        for (int g = 0; g < 16; ++g) {
            const float4 w4 = wr[g];
            sa = fmaf(w4.x, smem[H2O + g*4 + 0],
                 fmaf(w4.y, smem[H2O + g*4 + 1],
                 fmaf(w4.z, smem[H2O + g*4 + 2],
                 fmaf(w4.w, smem[H2O + g*4 + 3], sa))));
        }
        smem[H3O + t] = fmaxf(sa, 0.f);
    }
    __syncthreads();

    // ---- head: logits + log_softmax (wave 0) ----
    if (t < 64) {
        const int k = t & 31;
        float pr = smem[H3O + k] * Wmg[t];   // t = c*32 + k
#pragma unroll
        for (int d = 16; d >= 1; d >>= 1) pr += __shfl_xor(pr, d);
        const float l0 = __shfl(pr, 0) + blg[0];
        const float l1 = __shfl(pr, 32) + blg[1];
        if (t == 0) {
            const float mm = fmaxf(l0, l1);
            const float lse = mm + logf(expf(l0 - mm) + expf(l1 - mm));
            out[(size_t)b * 2 + 0] = l0 - lse;
            out[(size_t)b * 2 + 1] = l1 - lse;
        }
    }
}

extern "C" void kernel_launch(void* const* d_in, const int* in_sizes, int n_in,
                              void* d_out, int out_size, void* d_ws, size_t ws_size,
                              hipStream_t stream) {
    const float* x    = (const float*)d_in[0];
    const float* l1c0 = (const float*)d_in[1];
    const float* l1c1 = (const float*)d_in[2];
    const float* l1c2 = (const float*)d_in[3];
    const float* l1c3 = (const float*)d_in[4];
    const float* l1c4 = (const float*)d_in[5];
    const float* b1   = (const float*)d_in[6];
    const float* l2c0 = (const float*)d_in[7];
    const float* l2c1 = (const float*)d_in[8];
    const float* l2c2 = (const float*)d_in[9];
    const float* l2c3 = (const float*)d_in[10];
    const float* l2c4 = (const float*)d_in[11];
    const float* b2   = (const float*)d_in[12];
    const float* l3c0 = (const float*)d_in[13];
    const float* l3c1 = (const float*)d_in[14];
    const float* l3c2 = (const float*)d_in[15];
    const float* l3c3 = (const float*)d_in[16];
    const float* l3c4 = (const float*)d_in[17];
    const float* b3   = (const float*)d_in[18];
    const float* Wm   = (const float*)d_in[19];
    const float* bl   = (const float*)d_in[20];
    float* W3 = (float*)d_ws;  // 2048 floats scratch

    tt_setup_w3<<<8, 256, 0, stream>>>(l3c0, l3c1, l3c2, l3c3, l3c4, W3);
    tt_main<<<2048, 128, 0, stream>>>(x, l1c0, l1c1, l1c2, l1c3, l1c4, b1,
                                      l2c0, l2c1, l2c2, l2c3, l2c4, b2, b3,
                                      Wm, bl, W3, (float*)d_out);
}

// Round 8
// 250.768 us; speedup vs baseline: 1.1076x; 1.1076x over previous
//
#include <hip/hip_runtime.h>
#include <math.h>

// ---------------- LDS layout (floats), 128-thread (2-wave) block, 1 sample ----
#define WC3  0      // l1c3 [q3][m4][n4][q4]            128
#define WC2  128    // l1c2 [q2][m3][n3][q3]            128
#define WU1  256    // l2c1                              32  -> 288
#define T2A  288    // per-wave T2: wave v at T2A+v*1152, rows [32][36]  -> 2592
#define T3S  2592   // shared T3 rows [32][34] = 1088   -> 3680
#define HZ   288    // h1 zone (128 rows x 17 = 2176) overlays T2 after layer-1
#define DZ32 32     // D row s at HZ + 136*s + 32 (16 cols)
#define H3O  (HZ + 2112)   // 32  (C row 31 dead by then)
#define H2O  (HZ + 2176)   // 64
#define LDS_FLOATS 3680    // 14720 B -> 8+ blocks/CU

// Setup: dense layer-3 matrix W3[mi(32)][nj(64)] from TT cores (tiny).
__global__ void tt_setup_w3(const float* __restrict__ v0, const float* __restrict__ v1,
                            const float* __restrict__ v2, const float* __restrict__ v3,
                            const float* __restrict__ v4, float* __restrict__ w3) {
    int i = blockIdx.x * 256 + threadIdx.x;
    if (i >= 2048) return;
    int mi = i >> 6, nj = i & 63;
    int m1 = (mi >> 4) & 1, m2 = (mi >> 3) & 1, m3 = (mi >> 2) & 1, m4 = (mi >> 1) & 1, m5 = mi & 1;
    int n1 = (nj >> 4) & 3, n2 = (nj >> 3) & 1, n3 = (nj >> 2) & 1, n4 = (nj >> 1) & 1, n5 = nj & 1;
    float s = 0.f;
#pragma unroll
    for (int q1 = 0; q1 < 2; ++q1) {
        float a1 = v0[(m1 * 4 + n1) * 2 + q1];
#pragma unroll
        for (int q2 = 0; q2 < 2; ++q2) {
            float a2 = a1 * v1[((q1 * 2 + m2) * 2 + n2) * 2 + q2];
#pragma unroll
            for (int q3 = 0; q3 < 2; ++q3) {
                float a3 = a2 * v2[((q2 * 2 + m3) * 2 + n3) * 2 + q3];
#pragma unroll
                for (int q4 = 0; q4 < 2; ++q4)
                    s = fmaf(a3 * v3[((q3 * 2 + m4) * 2 + n4) * 2 + q4],
                             v4[(q4 * 2 + m5) * 2 + n5], s);
            }
        }
    }
    w3[i] = s;
}

__global__ __launch_bounds__(128, 2)
void tt_main(const float* __restrict__ x,
             const float* __restrict__ g0, const float* __restrict__ g1,
             const float* __restrict__ g2, const float* __restrict__ g3,
             const float* __restrict__ g4, const float* __restrict__ b1g,
             const float* __restrict__ u0, const float* __restrict__ u1,
             const float* __restrict__ u2, const float* __restrict__ u3,
             const float* __restrict__ u4, const float* __restrict__ b2g,
             const float* __restrict__ b3g,
             const float* __restrict__ Wmg, const float* __restrict__ blg,
             const float* __restrict__ w3g,
             float* __restrict__ out)
{
    __shared__ float smem[LDS_FLOATS];
    const int t = threadIdx.x;
    const int v = t >> 6;          // wave id = n2h handled by this wave
    const int l = t & 63;          // lane within wave
    const int b = blockIdx.x;
    const float* xb = x + (size_t)b * 12288;

    // ---- non-uniformly-indexed weights to LDS (shared) ----
    smem[WC3 + t] = g3[t];
    smem[WC2 + t] = g2[t];
    if (t < 32) smem[WU1 + t] = u1[t];
    __syncthreads();  // weights ready

    const int h = l & 1;                       // n4-half owned by this lane
    const int p = l >> 1;                      // prefix (n2l*8 + n3)
    const int rho = (p & 7) * 4 + (p >> 3);    // T2 row = n3*4 + n2l
    const int T2W = T2A + v * 1152;

    float regT4[18];                           // [jjl(2)][n1(3)][q1(3)]
#pragma unroll
    for (int i = 0; i < 18; ++i) regT4[i] = 0.f;

#pragma unroll
    for (int n1 = 0; n1 < 3; ++n1) {
        const int s = n1 * 2 + v;              // this wave's subslice
        const float4* xq = (const float4*)(xb + s * 2048 + l * 32);

        // ---- steps 1+2 chunked (register diet): per n4l load 8 x floats,
        //      form t1c[8], accumulate own + partner (shfl) into acc[16] ----
        float acc[16];
#pragma unroll
        for (int i = 0; i < 16; ++i) acc[i] = 0.f;
#pragma unroll
        for (int n4l = 0; n4l < 4; ++n4l) {
            const float4 xa = xq[n4l * 2 + 0];
            const float4 xc = xq[n4l * 2 + 1];
            float t1c[8];                      // [m5*2+q4]
#pragma unroll
            for (int m5 = 0; m5 < 4; ++m5)
#pragma unroll
            for (int q4 = 0; q4 < 2; ++q4) {
                const float* w = g4 + (q4 * 4 + m5) * 8;   // uniform: s_load
                t1c[m5 * 2 + q4] =
                    fmaf(xa.x, w[0], fmaf(xa.y, w[1], fmaf(xa.z, w[2], fmaf(xa.w, w[3],
                    fmaf(xc.x, w[4], fmaf(xc.y, w[5], fmaf(xc.z, w[6], xc.w * w[7])))))));
            }
            // own half: n4 = h*4+n4l, q3 = h
#pragma unroll
            for (int m4 = 0; m4 < 4; ++m4) {
                const float2 c = *(const float2*)&smem[WC3 + ((h * 4 + m4) * 8 + (h * 4 + n4l)) * 2];
#pragma unroll
                for (int m5 = 0; m5 < 4; ++m5)
                    acc[m4 * 4 + m5] = fmaf(t1c[m5 * 2 + 0], c.x,
                                       fmaf(t1c[m5 * 2 + 1], c.y, acc[m4 * 4 + m5]));
            }
            // partner half via shfl: n4 = (1-h)*4+n4l, q3 = h
            float t1s[8];
#pragma unroll
            for (int i = 0; i < 8; ++i) t1s[i] = __shfl_xor(t1c[i], 1);
#pragma unroll
            for (int m4 = 0; m4 < 4; ++m4) {
                const float2 c = *(const float2*)&smem[WC3 + ((h * 4 + m4) * 8 + ((1 - h) * 4 + n4l)) * 2];
#pragma unroll
                for (int m5 = 0; m5 < 4; ++m5)
                    acc[m4 * 4 + m5] = fmaf(t1s[m5 * 2 + 0], c.x,
                                       fmaf(t1s[m5 * 2 + 1], c.y, acc[m4 * 4 + m5]));
            }
        }
#pragma unroll
        for (int m45 = 0; m45 < 16; ++m45)
            smem[T2W + rho * 36 + m45 * 2 + h] = acc[m45];
        __syncthreads();   // T2 ready (R5-proven structure: explicit fence)

        // ---- step 3: contract n3(half per lane),q3 -> T3 rows (n2*4+m3) ----
        {
            const int n3h = l & 1;
            const int q2  = (l >> 1) & 1;
            const int m3  = (l >> 2) & 3;
            const int n2l = l >> 4;
            float o3[16];
#pragma unroll
            for (int i = 0; i < 16; ++i) o3[i] = 0.f;
#pragma unroll
            for (int n3l = 0; n3l < 4; ++n3l) {
                const int n3 = n3h * 4 + n3l;
                const int rb = T2W + (n3 * 4 + n2l) * 36;
                const float2 w = *(const float2*)&smem[WC2 + ((q2 * 4 + m3) * 8 + n3) * 2];
#pragma unroll
                for (int g = 0; g < 8; ++g) {
                    const float4 q = *(const float4*)&smem[rb + g * 4];
                    o3[g * 2 + 0] = fmaf(q.x, w.x, fmaf(q.y, w.y, o3[g * 2 + 0]));
                    o3[g * 2 + 1] = fmaf(q.z, w.x, fmaf(q.w, w.y, o3[g * 2 + 1]));
                }
            }
#pragma unroll
            for (int k = 0; k < 16; ++k) o3[k] += __shfl_xor(o3[k], 1);
            const int row3 = (v * 4 + n2l) * 4 + m3;       // n2*4 + m3
#pragma unroll
            for (int k = 0; k < 8; ++k) {
                const float val = n3h ? o3[8 + k] : o3[k];
                smem[T3S + row3 * 34 + (n3h * 8 + k) * 2 + q2] = val;
            }
        }
        __syncthreads();   // T3 ready (cross-wave)

        // ---- step 4: contract n2(8),q2 -> regT4 (C1 uniform s_load) ----
        {
            const int m3 = l >> 4, m4 = (l >> 2) & 3, m5 = l & 3;
            float2 zz[8];
#pragma unroll
            for (int n2 = 0; n2 < 8; ++n2)
                zz[n2] = *(const float2*)&smem[T3S + (n2 * 4 + m3) * 34 + (m4 * 4 + m5) * 2];
#pragma unroll
            for (int jjl = 0; jjl < 2; ++jjl) {
                const int jj = v * 2 + jjl;
#pragma unroll
                for (int q1 = 0; q1 < 3; ++q1) {
                    float sa = regT4[(jjl * 3 + n1) * 3 + q1];
#pragma unroll
                    for (int n2g = 0; n2g < 4; ++n2g) {
                        const float4 w = *(const float4*)(g1 + ((q1 * 4 + jj) * 8 + n2g * 2) * 2);
                        sa = fmaf(zz[n2g * 2].x,     w.x, sa);
                        sa = fmaf(zz[n2g * 2].y,     w.y, sa);
                        sa = fmaf(zz[n2g * 2 + 1].x, w.z, sa);
                        sa = fmaf(zz[n2g * 2 + 1].y, w.w, sa);
                    }
                    regT4[(jjl * 3 + n1) * 3 + q1] = sa;
                }
            }
        }
        __syncthreads();   // step4 reads done; T2/T3 reusable next iter (or HZ)
    } // n1

    // ---- step 5: contract n1,q1 + bias + relu -> h1 (pad-17 rows in HZ) ----
#pragma unroll
    for (int jjl = 0; jjl < 2; ++jjl) {
        const int jj = v * 2 + jjl;
#pragma unroll
        for (int m1 = 0; m1 < 8; ++m1) {
            const int e = m1 * 256 + jj * 64 + l;
            float sa = b1g[e];
#pragma unroll
            for (int n1 = 0; n1 < 3; ++n1)
#pragma unroll
            for (int q1 = 0; q1 < 3; ++q1)
                sa = fmaf(regT4[(jjl * 3 + n1) * 3 + q1], g0[(m1 * 3 + n1) * 3 + q1], sa);
            smem[HZ + (e >> 4) * 17 + (e & 15)] = fmaxf(sa, 0.f);
        }
    }
    __syncthreads();   // h1 ready

    // ---- L2a+L2b fused: h1 row p3=t -> B row (in-place, own row only) ----
    {
        float hv[16];
#pragma unroll
        for (int k = 0; k < 16; ++k) hv[k] = smem[HZ + t * 17 + k];
        float o[8];
#pragma unroll
        for (int i = 0; i < 8; ++i) o[i] = 0.f;
#pragma unroll
        for (int n4 = 0; n4 < 4; ++n4) {
            float a[4];   // [m5*2+q4]
#pragma unroll
            for (int m5 = 0; m5 < 2; ++m5)
#pragma unroll
            for (int q4 = 0; q4 < 2; ++q4) {
                float sa = hv[n4 * 4 + 0] * u4[(q4 * 2 + m5) * 4 + 0];
#pragma unroll
                for (int n5 = 1; n5 < 4; ++n5)
                    sa = fmaf(hv[n4 * 4 + n5], u4[(q4 * 2 + m5) * 4 + n5], sa);
                a[m5 * 2 + q4] = sa;
            }
#pragma unroll
            for (int q4 = 0; q4 < 2; ++q4) {
                const float a0 = a[0 * 2 + q4], a1 = a[1 * 2 + q4];
#pragma unroll
                for (int q3 = 0; q3 < 2; ++q3)
#pragma unroll
                for (int m4 = 0; m4 < 2; ++m4) {
                    const float w = u3[((q3 * 2 + m4) * 4 + n4) * 2 + q4];
                    o[(m4 * 2 + 0) * 2 + q3] = fmaf(a0, w, o[(m4 * 2 + 0) * 2 + q3]);
                    o[(m4 * 2 + 1) * 2 + q3] = fmaf(a1, w, o[(m4 * 2 + 1) * 2 + q3]);
                }
            }
        }
#pragma unroll
        for (int k = 0; k < 8; ++k) smem[HZ + t * 17 + k] = o[k];
    }
    __syncthreads();   // B ready (cross-wave)

    // ================= tail: R5-proven barrier-separated stages ==============
    // ---- L2c: contract n3(4),q3 -> C[p2=t<32][16] at HZ + 68*p2 ----
    if (t < 32) {
        float o[16];
#pragma unroll
        for (int i = 0; i < 16; ++i) o[i] = 0.f;
#pragma unroll
        for (int n3 = 0; n3 < 4; ++n3)
#pragma unroll
        for (int q3 = 0; q3 < 2; ++q3) {
            float zb[4];
#pragma unroll
            for (int m45 = 0; m45 < 4; ++m45)
                zb[m45] = smem[HZ + (t * 4 + n3) * 17 + m45 * 2 + q3];
#pragma unroll
            for (int m3 = 0; m3 < 2; ++m3)
#pragma unroll
            for (int q2 = 0; q2 < 2; ++q2) {
                const float w = u2[((q2 * 2 + m3) * 4 + n3) * 2 + q3];
#pragma unroll
                for (int m45 = 0; m45 < 4; ++m45)
                    o[(m3 * 4 + m45) * 2 + q2] = fmaf(zb[m45], w, o[(m3 * 4 + m45) * 2 + q2]);
            }
        }
#pragma unroll
        for (int k = 0; k < 16; ++k) smem[HZ + t * 68 + k] = o[k];
    }
    __syncthreads();

    // ---- L2d: contract n2(4),q2 -> D[s=16 rows][16] at HZ + 136*s + 32 ----
    if (t < 32) {
        const int n1 = t >> 2, m2 = (t >> 1) & 1, m3 = t & 1;
        float o[8];   // [m45*2+q1]
#pragma unroll
        for (int i = 0; i < 8; ++i) o[i] = 0.f;
#pragma unroll
        for (int n2 = 0; n2 < 4; ++n2)
#pragma unroll
        for (int q2 = 0; q2 < 2; ++q2) {
            float cb[4];
#pragma unroll
            for (int m45 = 0; m45 < 4; ++m45)
                cb[m45] = smem[HZ + (n1 * 4 + n2) * 68 + (m3 * 4 + m45) * 2 + q2];
#pragma unroll
            for (int q1 = 0; q1 < 2; ++q1) {
                const float w = smem[WU1 + ((q1 * 2 + m2) * 4 + n2) * 2 + q2];
#pragma unroll
                for (int m45 = 0; m45 < 4; ++m45)
                    o[m45 * 2 + q1] = fmaf(cb[m45], w, o[m45 * 2 + q1]);
            }
        }
#pragma unroll
        for (int m45 = 0; m45 < 4; ++m45)
#pragma unroll
        for (int q1 = 0; q1 < 2; ++q1)
            smem[HZ + (m2 * 8 + m3 * 4 + m45) * 136 + DZ32 + n1 * 2 + q1] = o[m45 * 2 + q1];
    }
    __syncthreads();

    // ---- L2e: contract n1(8),q1 + bias + relu -> h2 ----
    if (t < 16) {
        float o[4];
#pragma unroll
        for (int i = 0; i < 4; ++i) o[i] = 0.f;
#pragma unroll
        for (int n1 = 0; n1 < 8; ++n1)
#pragma unroll
        for (int q1 = 0; q1 < 2; ++q1) {
            const float dv = smem[HZ + t * 136 + DZ32 + n1 * 2 + q1];
#pragma unroll
            for (int m1 = 0; m1 < 4; ++m1)
                o[m1] = fmaf(dv, u0[(m1 * 8 + n1) * 2 + q1], o[m1]);
        }
#pragma unroll
        for (int m1 = 0; m1 < 4; ++m1)
            smem[H2O + m1 * 16 + t] = fmaxf(o[m1] + b2g[m1 * 16 + t], 0.f);
    }
    __syncthreads();

    // ---- layer 3 dense (W3 32x64 from d_ws) + relu ----
    if (t < 32) {
        const float4* wr = (const float4*)(w3g + t * 64);
        float sa = b3g[t];
#pragma unroll
        for (int g = 0; g < 16; ++g) {
            const float4 w4 = wr[g];
            sa = fmaf(w4.x, smem[H2O + g * 4 + 0],
                 fmaf(w4.y, smem[H2O + g * 4 + 1],
                 fmaf(w4.z, smem[H2O + g * 4 + 2],
                 fmaf(w4.w, smem[H2O + g * 4 + 3], sa))));
        }
        smem[H3O + t] = fmaxf(sa, 0.f);
    }
    __syncthreads();

    // ---- head: logits + log_softmax ----
    if (t < 64) {
        const int k = t & 31;
        float pr = smem[H3O + k] * Wmg[t];   // t = c*32 + k
#pragma unroll
        for (int d = 16; d >= 1; d >>= 1) pr += __shfl_xor(pr, d);
        const float l0 = __shfl(pr, 0) + blg[0];
        const float l1 = __shfl(pr, 32) + blg[1];
        if (t == 0) {
            const float mm = fmaxf(l0, l1);
            const float lse = mm + logf(expf(l0 - mm) + expf(l1 - mm));
            out[(size_t)b * 2 + 0] = l0 - lse;
            out[(size_t)b * 2 + 1] = l1 - lse;
        }
    }
}

extern "C" void kernel_launch(void* const* d_in, const int* in_sizes, int n_in,
                              void* d_out, int out_size, void* d_ws, size_t ws_size,
                              hipStream_t stream) {
    const float* x    = (const float*)d_in[0];
    const float* l1c0 = (const float*)d_in[1];
    const float* l1c1 = (const float*)d_in[2];
    const float* l1c2 = (const float*)d_in[3];
    const float* l1c3 = (const float*)d_in[4];
    const float* l1c4 = (const float*)d_in[5];
    const float* b1   = (const float*)d_in[6];
    const float* l2c0 = (const float*)d_in[7];
    const float* l2c1 = (const float*)d_in[8];
    const float* l2c2 = (const float*)d_in[9];
    const float* l2c3 = (const float*)d_in[10];
    const float* l2c4 = (const float*)d_in[11];
    const float* b2   = (const float*)d_in[12];
    const float* l3c0 = (const float*)d_in[13];
    const float* l3c1 = (const float*)d_in[14];
    const float* l3c2 = (const float*)d_in[15];
    const float* l3c3 = (const float*)d_in[16];
    const float* l3c4 = (const float*)d_in[17];
    const float* b3   = (const float*)d_in[18];
    const float* Wm   = (const float*)d_in[19];
    const float* bl   = (const float*)d_in[20];
    float* W3 = (float*)d_ws;  // 2048 floats scratch

    tt_setup_w3<<<8, 256, 0, stream>>>(l3c0, l3c1, l3c2, l3c3, l3c4, W3);
    tt_main<<<2048, 128, 0, stream>>>(x, l1c0, l1c1, l1c2, l1c3, l1c4, b1,
                                      l2c0, l2c1, l2c2, l2c3, l2c4, b2, b3,
                                      Wm, bl, W3, (float*)d_out);
}